// Round 8
// baseline (450.477 us; speedup 1.0000x reference)
//
#include <hip/hip_runtime.h>
#include <hip/hip_bf16.h>

namespace {

constexpr int B  = 4;
constexpr int P0 = 196608, P1 = 49152, P2 = 12288;
constexpr int DEG = 8;
constexpr float EPS = 1e-5f;
constexpr int NBLK3 = (P2 * B) / 64;   // 768 zblk partial rows
constexpr int RSL = 16;                // zred slices
constexpr int RPB = NBLK3 / RSL;       // 48 zblk rows per slice

typedef __attribute__((ext_vector_type(4))) float f32x4;
typedef __attribute__((ext_vector_type(8))) short s16x8;

__device__ __forceinline__ float b2f(unsigned short u) {
    union { unsigned int i; float f; } c; c.i = (unsigned int)u << 16; return c.f;
}
__device__ __forceinline__ unsigned short f2b(float f) {
    __hip_bfloat16 h = __float2bfloat16(f);   // RNE
    return *reinterpret_cast<unsigned short*>(&h);
}

// Chebyshev->power-basis weight combo:
//   xk@W = v0@(W0-W2) + v1@(W1-3W3) + v2@(2W2) + v3@(4W3),  v_k = L^k x.
__device__ __forceinline__ float chebw(const float* __restrict__ W,
                                       int k, int n, int N, int Cin) {
    int t = k / Cin, c = k - t * Cin;
    float v = W[(size_t)k * N + n];
    if (t == 0)      v = v - W[(size_t)(2 * Cin + c) * N + n];
    else if (t == 1) v = v - 3.f * W[(size_t)(3 * Cin + c) * N + n];
    else if (t == 2) v = 2.f * v;
    else             v = 4.f * v;
    return v;
}

// ---------------------------------------------------------------------------
// x: (B,P0,16) fp32  ->  xb: (P0,B,16) bf16
// ---------------------------------------------------------------------------
__global__ __launch_bounds__(256)
void x2p_kernel(const float* __restrict__ in, unsigned short* __restrict__ out)
{
    long idx = (long)blockIdx.x * blockDim.x + threadIdx.x;   // P0*B*2 total
    if (idx >= (long)P0 * B * 2) return;
    int  h = (int)(idx & 1);
    int  b = (int)((idx >> 1) & 3);
    long p = idx >> 3;
    const float* src = in + ((size_t)b * P0 + p) * 16 + h * 8;
    float4 v0 = *(const float4*)src;
    float4 v1 = *(const float4*)(src + 4);
    union { uint4 u; unsigned short s[8]; } o;
    o.s[0] = f2b(v0.x); o.s[1] = f2b(v0.y); o.s[2] = f2b(v0.z); o.s[3] = f2b(v0.w);
    o.s[4] = f2b(v1.x); o.s[5] = f2b(v1.y); o.s[6] = f2b(v1.z); o.s[7] = f2b(v1.w);
    *(uint4*)&out[((size_t)p * B + b) * 16 + h * 8] = o.u;
}

// ---------------------------------------------------------------------------
// Weight prep, one launch: W1/W2/W3 -> power-basis-combined, transposed bf16;
// mW1/mW2 -> fp32 transposed (contiguous head dot-products).
// ---------------------------------------------------------------------------
__global__ __launch_bounds__(256)
void wt_all_kernel(const float* __restrict__ W1, const float* __restrict__ W2,
                   const float* __restrict__ W3,
                   const float* __restrict__ mW1, const float* __restrict__ mW2,
                   unsigned short* __restrict__ Wt1, unsigned short* __restrict__ Wt2,
                   unsigned short* __restrict__ Wt3,
                   float* __restrict__ mW1t, float* __restrict__ mW2t)
{
    int i = blockIdx.x * 256 + threadIdx.x;
    if (i < 4096) {                       // W1: K=64 (Cin=16), N=64
        int n = i % 64, k = i / 64;
        Wt1[n * 64 + k] = f2b(chebw(W1, k, n, 64, 16));
    } else if (i < 36864) {               // W2: K=256 (Cin=64), N=128
        int j = i - 4096;
        int n = j % 128, k = j / 128;
        Wt2[n * 256 + k] = f2b(chebw(W2, k, n, 128, 64));
    } else if (i < 167936) {              // W3: K=512 (Cin=128), N=256
        int j = i - 36864;
        int n = j % 256, k = j / 256;
        Wt3[n * 512 + k] = f2b(chebw(W3, k, n, 256, 128));
    } else if (i < 299008) {              // mW1: (256,512) -> (512,256) fp32
        int j = i - 167936;
        int n = j % 512, k = j / 512;
        mW1t[(size_t)n * 256 + k] = mW1[j];
    } else if (i < 430080) {              // mW2: (512,256) -> (256,512) fp32
        int j = i - 299008;
        int n = j % 256, k = j / 256;
        mW2t[(size_t)n * 512 + k] = mW2[j];
    }
}

// ---------------------------------------------------------------------------
// Pure sparse gather step on (P, B*C) bf16 rows, fp32 accum:
//   out[p,:] = sum_d vals[p,d] * in[cols[p,d],:]          (power basis)
// Taps staged in LDS once per block. CV8 = B*C/8 uint4-units per row.
// ---------------------------------------------------------------------------
template <int CV8>
__global__ __launch_bounds__(256)
void lmul_v3_kernel(const unsigned short* __restrict__ in,
                    const int* __restrict__ cols, const float* __restrict__ vals,
                    unsigned short* __restrict__ out)
{
    constexpr int ROWS = 256 / CV8;
    __shared__ int   cs[ROWS * DEG];
    __shared__ float vs[ROWS * DEG];
    const int tid = threadIdx.x;
    const long r0 = (long)blockIdx.x * ROWS;
    if (tid < ROWS * DEG) {
        cs[tid] = cols[r0 * DEG + tid];
        vs[tid] = vals[r0 * DEG + tid];
    }
    __syncthreads();

    const int v  = tid & (CV8 - 1);
    const int lr = tid / CV8;
    const uint4* in16 = (const uint4*)in;

    float acc[8] = {0.f,0.f,0.f,0.f,0.f,0.f,0.f,0.f};
#pragma unroll
    for (int d = 0; d < DEG; ++d) {
        int   col = cs[lr * DEG + d];
        float w   = vs[lr * DEG + d];
        union { uint4 u; unsigned short s[8]; } x;
        x.u = in16[(size_t)col * CV8 + v];
#pragma unroll
        for (int j = 0; j < 8; ++j) acc[j] = fmaf(w, b2f(x.s[j]), acc[j]);
    }
    union { uint4 u; unsigned short s[8]; } ou;
#pragma unroll
    for (int j = 0; j < 8; ++j) ou.s[j] = f2b(acc[j]);
    ((uint4*)out)[(size_t)(r0 + lr) * CV8 + v] = ou.u;
}

// ---------------------------------------------------------------------------
// Stage-1 fused MM: KC=64, COUT=64, pool 4. W resident in registers,
// A-fragments read directly from global; grid-stride over 16-row wave-tiles.
// ---------------------------------------------------------------------------
__global__ __launch_bounds__(256)
void s1_mm_kernel(const unsigned short* __restrict__ t0,
                  const unsigned short* __restrict__ t1,
                  const unsigned short* __restrict__ t2,
                  const unsigned short* __restrict__ t3,
                  const unsigned short* __restrict__ Wt,
                  const float* __restrict__ bias,
                  const float* __restrict__ gam,
                  const float* __restrict__ bet,
                  unsigned short* __restrict__ out)
{
    const int wave = threadIdx.x >> 6;
    const int lane = threadIdx.x & 63;
    const int g    = lane >> 4;
    const int c16  = lane & 15;

    s16x8 wf[2][4];
#pragma unroll
    for (int ks = 0; ks < 2; ++ks)
#pragma unroll
        for (int n = 0; n < 4; ++n)
            wf[ks][n] = *(const s16x8*)&Wt[(size_t)(n * 16 + c16) * 64 + ks * 32 + g * 8];

    float bz[4], gz[4], tz[4];
#pragma unroll
    for (int n = 0; n < 4; ++n) {
        bz[n] = bias[n * 16 + c16];
        gz[n] = gam [n * 16 + c16];
        tz[n] = bet [n * 16 + c16];
    }

    const unsigned short* tb[4] = { t0, t1, t2, t3 };
    const int term0  = g >> 1;
    const int coloff = (g & 1) * 8;
    const int bb     = c16 >> 2;
    const int px     = c16 & 3;

    constexpr int NT = P0 / 4;
    const int wg     = blockIdx.x * 4 + wave;
    const int wstep  = gridDim.x * 4;

    for (int t = wg; t < NT; t += wstep) {
        size_t rowbase = ((size_t)(t * 4 + px) * 4 + bb) * 16 + coloff;
        s16x8 a0 = *(const s16x8*)&tb[term0    ][rowbase];
        s16x8 a1 = *(const s16x8*)&tb[term0 + 2][rowbase];

        f32x4 acc[4];
#pragma unroll
        for (int n = 0; n < 4; ++n) acc[n] = (f32x4){bz[n], bz[n], bz[n], bz[n]};
#pragma unroll
        for (int n = 0; n < 4; ++n)
            acc[n] = __builtin_amdgcn_mfma_f32_16x16x32_bf16(a0, wf[0][n], acc[n], 0, 0, 0);
#pragma unroll
        for (int n = 0; n < 4; ++n)
            acc[n] = __builtin_amdgcn_mfma_f32_16x16x32_bf16(a1, wf[1][n], acc[n], 0, 0, 0);

        float s[4] = {0,0,0,0}, q[4] = {0,0,0,0};
#pragma unroll
        for (int n = 0; n < 4; ++n)
#pragma unroll
            for (int r = 0; r < 4; ++r) {
                float v = acc[n][r];
                s[r] += v; q[r] += v * v;
            }
#pragma unroll
        for (int msk = 1; msk < 16; msk <<= 1)
#pragma unroll
            for (int r = 0; r < 4; ++r) {
                s[r] += __shfl_xor(s[r], msk, 64);
                q[r] += __shfl_xor(q[r], msk, 64);
            }
        float mu[4], rs[4];
#pragma unroll
        for (int r = 0; r < 4; ++r) {
            mu[r] = s[r] * (1.f / 64.f);
            float var = q[r] * (1.f / 64.f) - mu[r] * mu[r];
            rs[r] = rsqrtf(var + EPS);
        }
        size_t ro = ((size_t)t * 4 + g) * 64;
#pragma unroll
        for (int n = 0; n < 4; ++n) {
            float pv = 0.f;
#pragma unroll
            for (int r = 0; r < 4; ++r) {
                float h = fmaf(gz[n] * rs[r], acc[n][r] - mu[r], tz[n]);
                pv += fmaxf(h, 0.f);
            }
            out[ro + n * 16 + c16] = f2b(pv * 0.25f);
        }
    }
}

// ---------------------------------------------------------------------------
// Stages 2/3 fused MM v4: v3 + T14 async-STAGE split — next K-chunk's global
// loads are issued into registers BEFORE the current chunk's MFMA block, so
// HBM/L3 latency hides under MFMA; ds_write (next iter) waits vmcnt.
// ---------------------------------------------------------------------------
template <int CIN, int COUT, int GM, int GN, int POOL, int LOG2CIN>
__global__ __launch_bounds__(512)
void cheb_mm_v4_kernel(const unsigned short* __restrict__ t0,
                       const unsigned short* __restrict__ t1,
                       const unsigned short* __restrict__ t2,
                       const unsigned short* __restrict__ t3,
                       const unsigned short* __restrict__ Wt,
                       const float* __restrict__ bias,
                       const float* __restrict__ gam,
                       const float* __restrict__ bet,
                       void* __restrict__ outv)
{
    constexpr int KC   = 4 * CIN;
    constexpr int BM   = GM * 64;
    constexpr int NKCH = KC / 64;
    constexpr int AITS = BM * 8 / 512;
    constexpr int WITS = COUT * 8 / 512;

    __shared__ unsigned short As[BM * 64];     // swizzled, 128B/row
    __shared__ unsigned short Ws[COUT * 64];   // swizzled
    __shared__ float sq[BM][GN][2];

    const int tid  = threadIdx.x;
    const int wv   = tid >> 6;
    const int gm   = wv / GN;
    const int gn   = wv % GN;
    const int lane = tid & 63;
    const int g    = lane >> 4;
    const int c16  = lane & 15;

    const unsigned short* tb[4] = { t0, t1, t2, t3 };

    float bz[4], gz[4], tz[4];
#pragma unroll
    for (int n = 0; n < 4; ++n) {
        int col = gn * 64 + n * 16 + c16;
        bz[n] = bias[col]; gz[n] = gam[col]; tz[n] = bet[col];
    }

    f32x4 acc[4][4];
#pragma unroll
    for (int m = 0; m < 4; ++m)
#pragma unroll
        for (int n = 0; n < 4; ++n)
            acc[m][n] = (f32x4){bz[n], bz[n], bz[n], bz[n]};

    uint4 ra[AITS], rw[WITS];

    auto load_chunk = [&](int kc) {
#pragma unroll
        for (int it = 0; it < AITS; ++it) {
            int i = tid + it * 512;
            int row = i >> 3, v = i & 7;
            int k = kc * 64 + v * 8;
            int term = k >> LOG2CIN;
            int c = k & (CIN - 1);
            size_t srow;
            if constexpr (POOL == 4) {
                int pix = blockIdx.x * (BM / 4) + ((row >> 4) << 2) + (row & 3);
                int rb  = (row >> 2) & 3;
                srow = ((size_t)pix * B + rb) * CIN + c;
            } else {
                srow = ((size_t)(blockIdx.x * BM + row)) * CIN + c;
            }
            ra[it] = *(const uint4*)&tb[term][srow];
        }
#pragma unroll
        for (int it = 0; it < WITS; ++it) {
            int i = tid + it * 512;
            int co = i >> 3, v = i & 7;
            rw[it] = *(const uint4*)&Wt[(size_t)co * KC + kc * 64 + v * 8];
        }
    };
    auto write_chunk = [&]() {
#pragma unroll
        for (int it = 0; it < AITS; ++it) {
            int i = tid + it * 512;
            int row = i >> 3, v = i & 7;
            *(uint4*)((char*)As + row * 128 + ((v * 16) ^ ((row & 7) << 4))) = ra[it];
        }
#pragma unroll
        for (int it = 0; it < WITS; ++it) {
            int i = tid + it * 512;
            int co = i >> 3, v = i & 7;
            *(uint4*)((char*)Ws + co * 128 + ((v * 16) ^ ((co & 7) << 4))) = rw[it];
        }
    };

    load_chunk(0);
    for (int kc = 0; kc < NKCH; ++kc) {
        __syncthreads();              // prior chunk's LDS reads complete
        write_chunk();                // waits vmcnt internally
        __syncthreads();              // LDS visible
        if (kc + 1 < NKCH) load_chunk(kc + 1);   // issue next loads (async)
#pragma unroll
        for (int ks = 0; ks < 2; ++ks) {
            const int cb  = ks * 64 + g * 16;
            const int swz = cb ^ ((c16 & 7) << 4);
            s16x8 a[4], bw[4];
#pragma unroll
            for (int m = 0; m < 4; ++m)
                a[m] = *(const s16x8*)((const char*)As + (gm * 64 + m * 16 + c16) * 128 + swz);
#pragma unroll
            for (int n = 0; n < 4; ++n)
                bw[n] = *(const s16x8*)((const char*)Ws + (gn * 64 + n * 16 + c16) * 128 + swz);
#pragma unroll
            for (int n = 0; n < 4; ++n)
#pragma unroll
                for (int m = 0; m < 4; ++m)
                    acc[m][n] = __builtin_amdgcn_mfma_f32_16x16x32_bf16(a[m], bw[n], acc[m][n], 0, 0, 0);
        }
    }

    float sm[4][4], qm[4][4];
#pragma unroll
    for (int m = 0; m < 4; ++m)
#pragma unroll
        for (int r = 0; r < 4; ++r) { sm[m][r] = 0.f; qm[m][r] = 0.f; }
#pragma unroll
    for (int m = 0; m < 4; ++m)
#pragma unroll
        for (int n = 0; n < 4; ++n)
#pragma unroll
            for (int r = 0; r < 4; ++r) {
                float v = acc[m][n][r];
                sm[m][r] += v; qm[m][r] += v * v;
            }
#pragma unroll
    for (int msk = 1; msk < 16; msk <<= 1)
#pragma unroll
        for (int m = 0; m < 4; ++m)
#pragma unroll
            for (int r = 0; r < 4; ++r) {
                sm[m][r] += __shfl_xor(sm[m][r], msk, 64);
                qm[m][r] += __shfl_xor(qm[m][r], msk, 64);
            }
    __syncthreads();
    if (c16 == 0) {
#pragma unroll
        for (int m = 0; m < 4; ++m)
#pragma unroll
            for (int r = 0; r < 4; ++r) {
                sq[gm * 64 + m * 16 + g * 4 + r][gn][0] = sm[m][r];
                sq[gm * 64 + m * 16 + g * 4 + r][gn][1] = qm[m][r];
            }
    }
    __syncthreads();
    float mu[4][4], rs[4][4];
#pragma unroll
    for (int m = 0; m < 4; ++m)
#pragma unroll
        for (int r = 0; r < 4; ++r) {
            int row = gm * 64 + m * 16 + g * 4 + r;
            float ss = 0.f, qq = 0.f;
#pragma unroll
            for (int j = 0; j < GN; ++j) { ss += sq[row][j][0]; qq += sq[row][j][1]; }
            mu[m][r] = ss * (1.f / COUT);
            float var = qq * (1.f / COUT) - mu[m][r] * mu[m][r];
            rs[m][r] = rsqrtf(var + EPS);
        }

    if constexpr (POOL == 4) {
        unsigned short* outp = (unsigned short*)outv;
#pragma unroll
        for (int m = 0; m < 4; ++m) {
            size_t ro = ((size_t)(blockIdx.x * (BM / 16) + gm * 4 + m) * B + g) * COUT + gn * 64;
#pragma unroll
            for (int n = 0; n < 4; ++n) {
                float pv = 0.f;
#pragma unroll
                for (int r = 0; r < 4; ++r) {
                    float h = fmaf(gz[n] * rs[m][r], acc[m][n][r] - mu[m][r], tz[n]);
                    pv += fmaxf(h, 0.f);
                }
                outp[ro + n * 16 + c16] = f2b(pv * 0.25f);
            }
        }
    } else {
        float part[4][4];   // [n][r]
#pragma unroll
        for (int n = 0; n < 4; ++n)
#pragma unroll
            for (int r = 0; r < 4; ++r) part[n][r] = 0.f;
#pragma unroll
        for (int m = 0; m < 4; ++m)
#pragma unroll
            for (int n = 0; n < 4; ++n)
#pragma unroll
                for (int r = 0; r < 4; ++r) {
                    float h = fmaf(gz[n] * rs[m][r], acc[m][n][r] - mu[m][r], tz[n]);
                    part[n][r] += fmaxf(h, 0.f);
                }
#pragma unroll
        for (int n = 0; n < 4; ++n)
#pragma unroll
            for (int r = 0; r < 4; ++r) {
                part[n][r] += __shfl_xor(part[n][r], 16, 64);
                part[n][r] += __shfl_xor(part[n][r], 32, 64);
            }
        if (g == 0) {
            float* zb = (float*)outv + ((size_t)(blockIdx.x * GM + gm)) * (B * COUT);
#pragma unroll
            for (int n = 0; n < 4; ++n)
#pragma unroll
                for (int r = 0; r < 4; ++r)
                    zb[(size_t)r * COUT + gn * 64 + n * 16 + c16] = part[n][r];
        }
    }
}

// ---------------------------------------------------------------------------
// zblk (768, B*256) -> zp2 (RSL, B*256): coalesced parallel column reduce.
// ---------------------------------------------------------------------------
__global__ __launch_bounds__(256)
void zred_kernel(const float* __restrict__ zblk, float* __restrict__ zp2)
{
    int s   = blockIdx.x >> 2;
    int col = (blockIdx.x & 3) * 256 + threadIdx.x;
    float acc = 0.f;
#pragma unroll 8
    for (int r = 0; r < RPB; ++r)
        acc += zblk[(size_t)(s * RPB + r) * (B * 256) + col];
    zp2[(size_t)s * (B * 256) + col] = acc;
}

// ---------------------------------------------------------------------------
// Head stage A: z = (reduce zp2)/P2; hh[b][j] = relu(z[b]·mW1t[j] + mb1[j]).
// ---------------------------------------------------------------------------
__global__ __launch_bounds__(256)
void headA_kernel(const float* __restrict__ zp2, const float* __restrict__ mW1t,
                  const float* __restrict__ mb1, float* __restrict__ hh)
{
    __shared__ float zs[B * 256];
    __shared__ float ph[256];
    const int tid = threadIdx.x;
    for (int idx = tid; idx < B * 256; idx += 256) {
        float s = 0.f;
#pragma unroll
        for (int sl = 0; sl < RSL; ++sl) s += zp2[(size_t)sl * (B * 256) + idx];
        zs[idx] = s * (1.f / P2);
    }
    __syncthreads();
    const int jl = tid & 31, b = (tid >> 5) & 3, ig = tid >> 7;
    const int j  = blockIdx.x * 32 + jl;
    const float4* wrow = (const float4*)&mW1t[(size_t)j * 256 + ig * 128];
    const float*  zb   = &zs[b * 256 + ig * 128];
    float acc = 0.f;
#pragma unroll
    for (int i4 = 0; i4 < 32; ++i4) {
        float4 wv = wrow[i4];
        acc += zb[i4*4]*wv.x + zb[i4*4+1]*wv.y + zb[i4*4+2]*wv.z + zb[i4*4+3]*wv.w;
    }
    ph[tid] = acc;
    __syncthreads();
    if (tid < 128) {
        float a = ph[tid] + ph[tid + 128] + mb1[j];
        hh[b * 512 + j] = fmaxf(a, 0.f);
    }
}

// ---------------------------------------------------------------------------
// Head stage B: out[b][c] = hh[b]·mW2t[c] + mb2[c].
// ---------------------------------------------------------------------------
__global__ __launch_bounds__(256)
void headB_kernel(const float* __restrict__ hh, const float* __restrict__ mW2t,
                  const float* __restrict__ mb2, float* __restrict__ out)
{
    __shared__ float hs[B * 512];
    __shared__ float ph[256];
    const int tid = threadIdx.x;
    for (int idx = tid; idx < B * 512; idx += 256) hs[idx] = hh[idx];
    __syncthreads();
    const int cl = tid & 31, b = (tid >> 5) & 3, ig = tid >> 7;
    const int c  = blockIdx.x * 32 + cl;
    const float4* wrow = (const float4*)&mW2t[(size_t)c * 512 + ig * 256];
    const float*  hb   = &hs[b * 512 + ig * 256];
    float acc = 0.f;
#pragma unroll
    for (int j4 = 0; j4 < 64; ++j4) {
        float4 wv = wrow[j4];
        acc += hb[j4*4]*wv.x + hb[j4*4+1]*wv.y + hb[j4*4+2]*wv.z + hb[j4*4+3]*wv.w;
    }
    ph[tid] = acc;
    __syncthreads();
    if (tid < 128)
        out[b * 256 + c] = ph[tid] + ph[tid + 128] + mb2[c];
}

} // anonymous namespace

extern "C" void kernel_launch(void* const* d_in, const int* in_sizes, int n_in,
                              void* d_out, int out_size, void* d_ws, size_t ws_size,
                              hipStream_t stream)
{
    const float* x     = (const float*)d_in[0];
    const int*   cols1 = (const int*)  d_in[1];
    const float* vals1 = (const float*)d_in[2];
    const int*   cols2 = (const int*)  d_in[3];
    const float* vals2 = (const float*)d_in[4];
    const int*   cols3 = (const int*)  d_in[5];
    const float* vals3 = (const float*)d_in[6];
    const float* W1  = (const float*)d_in[7];
    const float* b1  = (const float*)d_in[8];
    const float* g1  = (const float*)d_in[9];
    const float* bt1 = (const float*)d_in[10];
    const float* W2  = (const float*)d_in[11];
    const float* b2  = (const float*)d_in[12];
    const float* g2  = (const float*)d_in[13];
    const float* bt2 = (const float*)d_in[14];
    const float* W3  = (const float*)d_in[15];
    const float* b3  = (const float*)d_in[16];
    const float* g3  = (const float*)d_in[17];
    const float* bt3 = (const float*)d_in[18];
    const float* mW1 = (const float*)d_in[19];
    const float* mb1 = (const float*)d_in[20];
    const float* mW2 = (const float*)d_in[21];
    const float* mb2 = (const float*)d_in[22];
    float* out = (float*)d_out;

    // ---- workspace layout (256B-aligned slots) ----
    char* w = (char*)d_ws;
    size_t off = 0;
    auto alloc = [&](size_t bytes) -> void* {
        void* p = w + off;
        off += (bytes + 255) & ~(size_t)255;
        return p;
    };
    const size_t E1 = (size_t)B * P0 * 16;
    unsigned short* xb  = (unsigned short*)alloc(E1 * 2);        // (P0,B,16)
    unsigned short* t_a = (unsigned short*)alloc(E1 * 2);
    unsigned short* t_b = (unsigned short*)alloc(E1 * 2);
    unsigned short* t_c = (unsigned short*)alloc(E1 * 2);
    unsigned short* h1  = (unsigned short*)alloc((size_t)P1 * B * 64 * 2);
    unsigned short* h2  = (unsigned short*)alloc((size_t)P2 * B * 128 * 2);
    unsigned short* Wt1 = (unsigned short*)alloc(64 * 64 * 2);
    unsigned short* Wt2 = (unsigned short*)alloc(256 * 128 * 2);
    unsigned short* Wt3 = (unsigned short*)alloc(512 * 256 * 2);
    float*          mW1t = (float*)alloc((size_t)512 * 256 * 4);
    float*          mW2t = (float*)alloc((size_t)256 * 512 * 4);
    float*          zblk = (float*)alloc((size_t)NBLK3 * B * 256 * 4);
    float*          zp2  = (float*)alloc((size_t)RSL * B * 256 * 4);
    float*          hh   = (float*)alloc((size_t)B * 512 * 4);

    // ---- precompute: layout transpose + weight prep (power-basis combo) ----
    x2p_kernel<<<(int)(((long)P0 * B * 2 + 255) / 256), 256, 0, stream>>>(x, xb);
    wt_all_kernel<<<(430080 + 255) / 256, 256, 0, stream>>>(
        W1, W2, W3, mW1, mW2, Wt1, Wt2, Wt3, mW1t, mW2t);

    // ---- Stage 1: P0, 16 -> 64, pool 4  (v_k = L^k x) ----
    {
        lmul_v3_kernel<8><<<P0 / 32, 256, 0, stream>>>(xb,  cols1, vals1, t_a);
        lmul_v3_kernel<8><<<P0 / 32, 256, 0, stream>>>(t_a, cols1, vals1, t_b);
        lmul_v3_kernel<8><<<P0 / 32, 256, 0, stream>>>(t_b, cols1, vals1, t_c);
        s1_mm_kernel<<<2048, 256, 0, stream>>>(xb, t_a, t_b, t_c, Wt1, b1, g1, bt1, h1);
    }
    // ---- Stage 2: P1, 64 -> 128, pool 4 ----
    {
        lmul_v3_kernel<32><<<P1 / 8, 256, 0, stream>>>(h1,  cols2, vals2, t_a);
        lmul_v3_kernel<32><<<P1 / 8, 256, 0, stream>>>(t_a, cols2, vals2, t_b);
        lmul_v3_kernel<32><<<P1 / 8, 256, 0, stream>>>(t_b, cols2, vals2, t_c);
        cheb_mm_v4_kernel<64, 128, 4, 2, 4, 6><<<(P1 * B) / 256, 512, 0, stream>>>(
            h1, t_a, t_b, t_c, Wt2, b2, g2, bt2, h2);
    }
    // ---- Stage 3: P2, 128 -> 256, no pool; emits colsum partials ----
    {
        lmul_v3_kernel<64><<<P2 / 4, 256, 0, stream>>>(h2,  cols3, vals3, t_a);
        lmul_v3_kernel<64><<<P2 / 4, 256, 0, stream>>>(t_a, cols3, vals3, t_b);
        lmul_v3_kernel<64><<<P2 / 4, 256, 0, stream>>>(t_b, cols3, vals3, t_c);
        cheb_mm_v4_kernel<128, 256, 2, 4, 1, 7><<<(P2 * B) / 128, 512, 0, stream>>>(
            h2, t_a, t_b, t_c, Wt3, b3, g3, bt3, zblk);
    }
    // ---- z reduce + head ----
    zred_kernel<<<RSL * 4, 256, 0, stream>>>(zblk, zp2);
    headA_kernel<<<16, 256, 0, stream>>>(zp2, mW1t, mb1, hh);
    headB_kernel<<<8, 256, 0, stream>>>(hh, mW2t, mb2, out);

    (void)in_sizes; (void)n_in; (void)out_size; (void)ws_size;
}

// Round 9
// 383.677 us; speedup vs baseline: 1.1741x; 1.1741x over previous
//
#include <hip/hip_runtime.h>
#include <hip/hip_bf16.h>

namespace {

constexpr int B  = 4;
constexpr int P0 = 196608, P1 = 49152, P2 = 12288;
constexpr int DEG = 8;
constexpr float EPS = 1e-5f;
constexpr int NBLK3 = (P2 * B) / 64;   // 768 zblk partial rows
constexpr int RSL = 16;                // zred slices
constexpr int RPB = NBLK3 / RSL;       // 48 zblk rows per slice

typedef __attribute__((ext_vector_type(4))) float f32x4;
typedef __attribute__((ext_vector_type(8))) short s16x8;

__device__ __forceinline__ float b2f(unsigned short u) {
    union { unsigned int i; float f; } c; c.i = (unsigned int)u << 16; return c.f;
}
__device__ __forceinline__ unsigned short f2b(float f) {
    __hip_bfloat16 h = __float2bfloat16(f);   // RNE
    return *reinterpret_cast<unsigned short*>(&h);
}

// async global->LDS: 16B per lane, LDS dest = uniform base + lane*16
__device__ __forceinline__ void gload_lds16(const void* gsrc, void* ldst) {
    __builtin_amdgcn_global_load_lds(
        (const __attribute__((address_space(1))) void*)gsrc,
        (__attribute__((address_space(3))) void*)ldst, 16, 0, 0);
}

// Chebyshev->power-basis weight combo:
//   xk@W = v0@(W0-W2) + v1@(W1-3W3) + v2@(2W2) + v3@(4W3),  v_k = L^k x.
__device__ __forceinline__ float chebw(const float* __restrict__ W,
                                       int k, int n, int N, int Cin) {
    int t = k / Cin, c = k - t * Cin;
    float v = W[(size_t)k * N + n];
    if (t == 0)      v = v - W[(size_t)(2 * Cin + c) * N + n];
    else if (t == 1) v = v - 3.f * W[(size_t)(3 * Cin + c) * N + n];
    else if (t == 2) v = 2.f * v;
    else             v = 4.f * v;
    return v;
}

// ---------------------------------------------------------------------------
// x: (B,P0,16) fp32  ->  xb: (P0,B,16) bf16
// ---------------------------------------------------------------------------
__global__ __launch_bounds__(256)
void x2p_kernel(const float* __restrict__ in, unsigned short* __restrict__ out)
{
    long idx = (long)blockIdx.x * blockDim.x + threadIdx.x;   // P0*B*2 total
    if (idx >= (long)P0 * B * 2) return;
    int  h = (int)(idx & 1);
    int  b = (int)((idx >> 1) & 3);
    long p = idx >> 3;
    const float* src = in + ((size_t)b * P0 + p) * 16 + h * 8;
    float4 v0 = *(const float4*)src;
    float4 v1 = *(const float4*)(src + 4);
    union { uint4 u; unsigned short s[8]; } o;
    o.s[0] = f2b(v0.x); o.s[1] = f2b(v0.y); o.s[2] = f2b(v0.z); o.s[3] = f2b(v0.w);
    o.s[4] = f2b(v1.x); o.s[5] = f2b(v1.y); o.s[6] = f2b(v1.z); o.s[7] = f2b(v1.w);
    *(uint4*)&out[((size_t)p * B + b) * 16 + h * 8] = o.u;
}

// ---------------------------------------------------------------------------
// Weight prep, one launch: W1/W2/W3 -> power-basis-combined, transposed bf16;
// mW1/mW2 -> fp32 transposed (contiguous head dot-products).
// ---------------------------------------------------------------------------
__global__ __launch_bounds__(256)
void wt_all_kernel(const float* __restrict__ W1, const float* __restrict__ W2,
                   const float* __restrict__ W3,
                   const float* __restrict__ mW1, const float* __restrict__ mW2,
                   unsigned short* __restrict__ Wt1, unsigned short* __restrict__ Wt2,
                   unsigned short* __restrict__ Wt3,
                   float* __restrict__ mW1t, float* __restrict__ mW2t)
{
    int i = blockIdx.x * 256 + threadIdx.x;
    if (i < 4096) {                       // W1: K=64 (Cin=16), N=64
        int n = i % 64, k = i / 64;
        Wt1[n * 64 + k] = f2b(chebw(W1, k, n, 64, 16));
    } else if (i < 36864) {               // W2: K=256 (Cin=64), N=128
        int j = i - 4096;
        int n = j % 128, k = j / 128;
        Wt2[n * 256 + k] = f2b(chebw(W2, k, n, 128, 64));
    } else if (i < 167936) {              // W3: K=512 (Cin=128), N=256
        int j = i - 36864;
        int n = j % 256, k = j / 256;
        Wt3[n * 512 + k] = f2b(chebw(W3, k, n, 256, 128));
    } else if (i < 299008) {              // mW1: (256,512) -> (512,256) fp32
        int j = i - 167936;
        int n = j % 512, k = j / 512;
        mW1t[(size_t)n * 256 + k] = mW1[j];
    } else if (i < 430080) {              // mW2: (512,256) -> (256,512) fp32
        int j = i - 299008;
        int n = j % 256, k = j / 256;
        mW2t[(size_t)n * 512 + k] = mW2[j];
    }
}

// ---------------------------------------------------------------------------
// Pure sparse gather step on (P, B*C) bf16 rows, fp32 accum (power basis).
// ---------------------------------------------------------------------------
template <int CV8>
__global__ __launch_bounds__(256)
void lmul_v3_kernel(const unsigned short* __restrict__ in,
                    const int* __restrict__ cols, const float* __restrict__ vals,
                    unsigned short* __restrict__ out)
{
    constexpr int ROWS = 256 / CV8;
    __shared__ int   cs[ROWS * DEG];
    __shared__ float vs[ROWS * DEG];
    const int tid = threadIdx.x;
    const long r0 = (long)blockIdx.x * ROWS;
    if (tid < ROWS * DEG) {
        cs[tid] = cols[r0 * DEG + tid];
        vs[tid] = vals[r0 * DEG + tid];
    }
    __syncthreads();

    const int v  = tid & (CV8 - 1);
    const int lr = tid / CV8;
    const uint4* in16 = (const uint4*)in;

    float acc[8] = {0.f,0.f,0.f,0.f,0.f,0.f,0.f,0.f};
#pragma unroll
    for (int d = 0; d < DEG; ++d) {
        int   col = cs[lr * DEG + d];
        float w   = vs[lr * DEG + d];
        union { uint4 u; unsigned short s[8]; } x;
        x.u = in16[(size_t)col * CV8 + v];
#pragma unroll
        for (int j = 0; j < 8; ++j) acc[j] = fmaf(w, b2f(x.s[j]), acc[j]);
    }
    union { uint4 u; unsigned short s[8]; } ou;
#pragma unroll
    for (int j = 0; j < 8; ++j) ou.s[j] = f2b(acc[j]);
    ((uint4*)out)[(size_t)(r0 + lr) * CV8 + v] = ou.u;
}

// ---------------------------------------------------------------------------
// Stage-1 fused MM: KC=64, COUT=64, pool 4. W resident in registers,
// A-fragments read directly from global; grid-stride over 16-row wave-tiles.
// ---------------------------------------------------------------------------
__global__ __launch_bounds__(256)
void s1_mm_kernel(const unsigned short* __restrict__ t0,
                  const unsigned short* __restrict__ t1,
                  const unsigned short* __restrict__ t2,
                  const unsigned short* __restrict__ t3,
                  const unsigned short* __restrict__ Wt,
                  const float* __restrict__ bias,
                  const float* __restrict__ gam,
                  const float* __restrict__ bet,
                  unsigned short* __restrict__ out)
{
    const int wave = threadIdx.x >> 6;
    const int lane = threadIdx.x & 63;
    const int g    = lane >> 4;
    const int c16  = lane & 15;

    s16x8 wf[2][4];
#pragma unroll
    for (int ks = 0; ks < 2; ++ks)
#pragma unroll
        for (int n = 0; n < 4; ++n)
            wf[ks][n] = *(const s16x8*)&Wt[(size_t)(n * 16 + c16) * 64 + ks * 32 + g * 8];

    float bz[4], gz[4], tz[4];
#pragma unroll
    for (int n = 0; n < 4; ++n) {
        bz[n] = bias[n * 16 + c16];
        gz[n] = gam [n * 16 + c16];
        tz[n] = bet [n * 16 + c16];
    }

    const unsigned short* tb[4] = { t0, t1, t2, t3 };
    const int term0  = g >> 1;
    const int coloff = (g & 1) * 8;
    const int bb     = c16 >> 2;
    const int px     = c16 & 3;

    constexpr int NT = P0 / 4;
    const int wg     = blockIdx.x * 4 + wave;
    const int wstep  = gridDim.x * 4;

    for (int t = wg; t < NT; t += wstep) {
        size_t rowbase = ((size_t)(t * 4 + px) * 4 + bb) * 16 + coloff;
        s16x8 a0 = *(const s16x8*)&tb[term0    ][rowbase];
        s16x8 a1 = *(const s16x8*)&tb[term0 + 2][rowbase];

        f32x4 acc[4];
#pragma unroll
        for (int n = 0; n < 4; ++n) acc[n] = (f32x4){bz[n], bz[n], bz[n], bz[n]};
#pragma unroll
        for (int n = 0; n < 4; ++n)
            acc[n] = __builtin_amdgcn_mfma_f32_16x16x32_bf16(a0, wf[0][n], acc[n], 0, 0, 0);
#pragma unroll
        for (int n = 0; n < 4; ++n)
            acc[n] = __builtin_amdgcn_mfma_f32_16x16x32_bf16(a1, wf[1][n], acc[n], 0, 0, 0);

        float s[4] = {0,0,0,0}, q[4] = {0,0,0,0};
#pragma unroll
        for (int n = 0; n < 4; ++n)
#pragma unroll
            for (int r = 0; r < 4; ++r) {
                float v = acc[n][r];
                s[r] += v; q[r] += v * v;
            }
#pragma unroll
        for (int msk = 1; msk < 16; msk <<= 1)
#pragma unroll
            for (int r = 0; r < 4; ++r) {
                s[r] += __shfl_xor(s[r], msk, 64);
                q[r] += __shfl_xor(q[r], msk, 64);
            }
        float mu[4], rs[4];
#pragma unroll
        for (int r = 0; r < 4; ++r) {
            mu[r] = s[r] * (1.f / 64.f);
            float var = q[r] * (1.f / 64.f) - mu[r] * mu[r];
            rs[r] = rsqrtf(var + EPS);
        }
        size_t ro = ((size_t)t * 4 + g) * 64;
#pragma unroll
        for (int n = 0; n < 4; ++n) {
            float pv = 0.f;
#pragma unroll
            for (int r = 0; r < 4; ++r) {
                float h = fmaf(gz[n] * rs[r], acc[n][r] - mu[r], tz[n]);
                pv += fmaxf(h, 0.f);
            }
            out[ro + n * 16 + c16] = f2b(pv * 0.25f);
        }
    }
}

// ---------------------------------------------------------------------------
// Stages 2/3 fused MM v5: async global_load_lds staging + LDS double-buffer,
// ONE barrier per K-chunk. Next chunk's loads fly during this chunk's MFMA;
// the next barrier's vmcnt(0) drain is exactly where the data is needed.
// Swizzle (T2) via inverse-swizzled per-lane GLOBAL source + linear LDS dest
// (guide rule #21); swizzled read unchanged (0 bank conflicts, round-6 PMC).
// Per chunk, term is uniform: chunk==term (CIN=64) or term=kc>>1 (CIN=128).
// ---------------------------------------------------------------------------
template <int CIN, int COUT, int GM, int GN, int POOL, int LOG2CIN>
__global__ __launch_bounds__(512)
void cheb_mm_v5_kernel(const unsigned short* __restrict__ t0,
                       const unsigned short* __restrict__ t1,
                       const unsigned short* __restrict__ t2,
                       const unsigned short* __restrict__ t3,
                       const unsigned short* __restrict__ Wt,
                       const float* __restrict__ bias,
                       const float* __restrict__ gam,
                       const float* __restrict__ bet,
                       void* __restrict__ outv)
{
    constexpr int KC     = 4 * CIN;
    constexpr int BM     = GM * 64;
    constexpr int NKCH   = KC / 64;
    constexpr int ACALLS = BM / 64;     // gload_lds calls per wave (A), 8 rows each
    constexpr int WCALLS = COUT / 64;

    __shared__ unsigned short As[2][BM * 64];     // 128B/row, dbuf
    __shared__ unsigned short Ws[2][COUT * 64];
    __shared__ float sq[BM][GN][2];

    const int tid  = threadIdx.x;
    const int wv   = tid >> 6;
    const int gm   = wv / GN;
    const int gn   = wv % GN;
    const int lane = tid & 63;
    const int g    = lane >> 4;
    const int c16  = lane & 15;

    const unsigned short* tb[4] = { t0, t1, t2, t3 };

    float bz[4], gz[4], tz[4];
#pragma unroll
    for (int n = 0; n < 4; ++n) {
        int col = gn * 64 + n * 16 + c16;
        bz[n] = bias[col]; gz[n] = gam[col]; tz[n] = bet[col];
    }

    f32x4 acc[4][4];
#pragma unroll
    for (int m = 0; m < 4; ++m)
#pragma unroll
        for (int n = 0; n < 4; ++n)
            acc[m][n] = (f32x4){bz[n], bz[n], bz[n], bz[n]};

    // ---- async stage of chunk kc into buffer bb (fire-and-forget) ----
    auto stage = [&](int kc, int bb) {
        int term, cbase;
        if constexpr (LOG2CIN == 6) { term = kc;      cbase = 0; }
        else                        { term = kc >> 1; cbase = (kc & 1) * 64; }
        const unsigned short* tp = tb[term];
#pragma unroll
        for (int a = 0; a < ACALLS; ++a) {
            int ci   = wv * ACALLS + a;
            int row  = ci * 8 + (lane >> 3);
            int srcb = ((lane & 7) * 16) ^ ((row & 7) << 4);   // inverse swizzle
            size_t rowbase;
            if constexpr (POOL == 4) {
                int pix = blockIdx.x * (BM / 4) + ((row >> 4) << 2) + (row & 3);
                int rb  = (row >> 2) & 3;
                rowbase = ((size_t)pix * B + rb) * CIN + cbase;
            } else {
                rowbase = ((size_t)(blockIdx.x * BM + row)) * CIN + cbase;
            }
            gload_lds16((const char*)(tp + rowbase) + srcb, &As[bb][ci * 512]);
        }
#pragma unroll
        for (int a = 0; a < WCALLS; ++a) {
            int ci   = wv * WCALLS + a;
            int co   = ci * 8 + (lane >> 3);
            int srcb = ((lane & 7) * 16) ^ ((co & 7) << 4);
            gload_lds16((const char*)(Wt + (size_t)co * KC + kc * 64) + srcb,
                        &Ws[bb][ci * 512]);
        }
    };

    int cur = 0;
    stage(0, 0);
    for (int kc = 0; kc < NKCH; ++kc) {
        __syncthreads();                       // vmcnt drain: buf[cur] ready
        if (kc + 1 < NKCH) stage(kc + 1, cur ^ 1);   // overlap with MFMA below
        const char* Ab = (const char*)As[cur];
        const char* Wb = (const char*)Ws[cur];
#pragma unroll
        for (int ks = 0; ks < 2; ++ks) {
            const int swz = (ks * 64 + g * 16) ^ ((c16 & 7) << 4);
            s16x8 a[4], bw[4];
#pragma unroll
            for (int m = 0; m < 4; ++m)
                a[m] = *(const s16x8*)(Ab + (gm * 64 + m * 16 + c16) * 128 + swz);
#pragma unroll
            for (int n = 0; n < 4; ++n)
                bw[n] = *(const s16x8*)(Wb + (gn * 64 + n * 16 + c16) * 128 + swz);
#pragma unroll
            for (int n = 0; n < 4; ++n)
#pragma unroll
                for (int m = 0; m < 4; ++m)
                    acc[m][n] = __builtin_amdgcn_mfma_f32_16x16x32_bf16(a[m], bw[n], acc[m][n], 0, 0, 0);
        }
        cur ^= 1;
    }

    // ---- LN stats: per-wave column-slice partials, cross-wave via sq ----
    float sm[4][4], qm[4][4];
#pragma unroll
    for (int m = 0; m < 4; ++m)
#pragma unroll
        for (int r = 0; r < 4; ++r) { sm[m][r] = 0.f; qm[m][r] = 0.f; }
#pragma unroll
    for (int m = 0; m < 4; ++m)
#pragma unroll
        for (int n = 0; n < 4; ++n)
#pragma unroll
            for (int r = 0; r < 4; ++r) {
                float v = acc[m][n][r];
                sm[m][r] += v; qm[m][r] += v * v;
            }
#pragma unroll
    for (int msk = 1; msk < 16; msk <<= 1)
#pragma unroll
        for (int m = 0; m < 4; ++m)
#pragma unroll
            for (int r = 0; r < 4; ++r) {
                sm[m][r] += __shfl_xor(sm[m][r], msk, 64);
                qm[m][r] += __shfl_xor(qm[m][r], msk, 64);
            }
    __syncthreads();
    if (c16 == 0) {
#pragma unroll
        for (int m = 0; m < 4; ++m)
#pragma unroll
            for (int r = 0; r < 4; ++r) {
                sq[gm * 64 + m * 16 + g * 4 + r][gn][0] = sm[m][r];
                sq[gm * 64 + m * 16 + g * 4 + r][gn][1] = qm[m][r];
            }
    }
    __syncthreads();
    float mu[4][4], rs[4][4];
#pragma unroll
    for (int m = 0; m < 4; ++m)
#pragma unroll
        for (int r = 0; r < 4; ++r) {
            int row = gm * 64 + m * 16 + g * 4 + r;
            float ss = 0.f, qq = 0.f;
#pragma unroll
            for (int j = 0; j < GN; ++j) { ss += sq[row][j][0]; qq += sq[row][j][1]; }
            mu[m][r] = ss * (1.f / COUT);
            float var = qq * (1.f / COUT) - mu[m][r] * mu[m][r];
            rs[m][r] = rsqrtf(var + EPS);
        }

    if constexpr (POOL == 4) {
        unsigned short* outp = (unsigned short*)outv;
#pragma unroll
        for (int m = 0; m < 4; ++m) {
            size_t ro = ((size_t)(blockIdx.x * (BM / 16) + gm * 4 + m) * B + g) * COUT + gn * 64;
#pragma unroll
            for (int n = 0; n < 4; ++n) {
                float pv = 0.f;
#pragma unroll
                for (int r = 0; r < 4; ++r) {
                    float h = fmaf(gz[n] * rs[m][r], acc[m][n][r] - mu[m][r], tz[n]);
                    pv += fmaxf(h, 0.f);
                }
                outp[ro + n * 16 + c16] = f2b(pv * 0.25f);
            }
        }
    } else {
        float part[4][4];   // [n][r]; flat-row batch = reg index r
#pragma unroll
        for (int n = 0; n < 4; ++n)
#pragma unroll
            for (int r = 0; r < 4; ++r) part[n][r] = 0.f;
#pragma unroll
        for (int m = 0; m < 4; ++m)
#pragma unroll
            for (int n = 0; n < 4; ++n)
#pragma unroll
                for (int r = 0; r < 4; ++r) {
                    float h = fmaf(gz[n] * rs[m][r], acc[m][n][r] - mu[m][r], tz[n]);
                    part[n][r] += fmaxf(h, 0.f);
                }
#pragma unroll
        for (int n = 0; n < 4; ++n)
#pragma unroll
            for (int r = 0; r < 4; ++r) {
                part[n][r] += __shfl_xor(part[n][r], 16, 64);
                part[n][r] += __shfl_xor(part[n][r], 32, 64);
            }
        if (g == 0) {
            float* zb = (float*)outv + ((size_t)(blockIdx.x * GM + gm)) * (B * COUT);
#pragma unroll
            for (int n = 0; n < 4; ++n)
#pragma unroll
                for (int r = 0; r < 4; ++r)
                    zb[(size_t)r * COUT + gn * 64 + n * 16 + c16] = part[n][r];
        }
    }
}

// ---------------------------------------------------------------------------
// zblk (768, B*256) -> zp2 (RSL, B*256): coalesced parallel column reduce.
// ---------------------------------------------------------------------------
__global__ __launch_bounds__(256)
void zred_kernel(const float* __restrict__ zblk, float* __restrict__ zp2)
{
    int s   = blockIdx.x >> 2;
    int col = (blockIdx.x & 3) * 256 + threadIdx.x;
    float acc = 0.f;
#pragma unroll 8
    for (int r = 0; r < RPB; ++r)
        acc += zblk[(size_t)(s * RPB + r) * (B * 256) + col];
    zp2[(size_t)s * (B * 256) + col] = acc;
}

// ---------------------------------------------------------------------------
// Head stage A: z = (reduce zp2)/P2; hh[b][j] = relu(z[b]·mW1t[j] + mb1[j]).
// ---------------------------------------------------------------------------
__global__ __launch_bounds__(256)
void headA_kernel(const float* __restrict__ zp2, const float* __restrict__ mW1t,
                  const float* __restrict__ mb1, float* __restrict__ hh)
{
    __shared__ float zs[B * 256];
    __shared__ float ph[256];
    const int tid = threadIdx.x;
    for (int idx = tid; idx < B * 256; idx += 256) {
        float s = 0.f;
#pragma unroll
        for (int sl = 0; sl < RSL; ++sl) s += zp2[(size_t)sl * (B * 256) + idx];
        zs[idx] = s * (1.f / P2);
    }
    __syncthreads();
    const int jl = tid & 31, b = (tid >> 5) & 3, ig = tid >> 7;
    const int j  = blockIdx.x * 32 + jl;
    const float4* wrow = (const float4*)&mW1t[(size_t)j * 256 + ig * 128];
    const float*  zb   = &zs[b * 256 + ig * 128];
    float acc = 0.f;
#pragma unroll
    for (int i4 = 0; i4 < 32; ++i4) {
        float4 wv = wrow[i4];
        acc += zb[i4*4]*wv.x + zb[i4*4+1]*wv.y + zb[i4*4+2]*wv.z + zb[i4*4+3]*wv.w;
    }
    ph[tid] = acc;
    __syncthreads();
    if (tid < 128) {
        float a = ph[tid] + ph[tid + 128] + mb1[j];
        hh[b * 512 + j] = fmaxf(a, 0.f);
    }
}

// ---------------------------------------------------------------------------
// Head stage B: out[b][c] = hh[b]·mW2t[c] + mb2[c].
// ---------------------------------------------------------------------------
__global__ __launch_bounds__(256)
void headB_kernel(const float* __restrict__ hh, const float* __restrict__ mW2t,
                  const float* __restrict__ mb2, float* __restrict__ out)
{
    __shared__ float hs[B * 512];
    __shared__ float ph[256];
    const int tid = threadIdx.x;
    for (int idx = tid; idx < B * 512; idx += 256) hs[idx] = hh[idx];
    __syncthreads();
    const int cl = tid & 31, b = (tid >> 5) & 3, ig = tid >> 7;
    const int c  = blockIdx.x * 32 + cl;
    const float4* wrow = (const float4*)&mW2t[(size_t)c * 512 + ig * 256];
    const float*  hb   = &hs[b * 512 + ig * 256];
    float acc = 0.f;
#pragma unroll
    for (int j4 = 0; j4 < 64; ++j4) {
        float4 wv = wrow[j4];
        acc += hb[j4*4]*wv.x + hb[j4*4+1]*wv.y + hb[j4*4+2]*wv.z + hb[j4*4+3]*wv.w;
    }
    ph[tid] = acc;
    __syncthreads();
    if (tid < 128)
        out[b * 256 + c] = ph[tid] + ph[tid + 128] + mb2[c];
}

} // anonymous namespace

extern "C" void kernel_launch(void* const* d_in, const int* in_sizes, int n_in,
                              void* d_out, int out_size, void* d_ws, size_t ws_size,
                              hipStream_t stream)
{
    const float* x     = (const float*)d_in[0];
    const int*   cols1 = (const int*)  d_in[1];
    const float* vals1 = (const float*)d_in[2];
    const int*   cols2 = (const int*)  d_in[3];
    const float* vals2 = (const float*)d_in[4];
    const int*   cols3 = (const int*)  d_in[5];
    const float* vals3 = (const float*)d_in[6];
    const float* W1  = (const float*)d_in[7];
    const float* b1  = (const float*)d_in[8];
    const float* g1  = (const float*)d_in[9];
    const float* bt1 = (const float*)d_in[10];
    const float* W2  = (const float*)d_in[11];
    const float* b2  = (const float*)d_in[12];
    const float* g2  = (const float*)d_in[13];
    const float* bt2 = (const float*)d_in[14];
    const float* W3  = (const float*)d_in[15];
    const float* b3  = (const float*)d_in[16];
    const float* g3  = (const float*)d_in[17];
    const float* bt3 = (const float*)d_in[18];
    const float* mW1 = (const float*)d_in[19];
    const float* mb1 = (const float*)d_in[20];
    const float* mW2 = (const float*)d_in[21];
    const float* mb2 = (const float*)d_in[22];
    float* out = (float*)d_out;

    // ---- workspace layout (256B-aligned slots) ----
    char* w = (char*)d_ws;
    size_t off = 0;
    auto alloc = [&](size_t bytes) -> void* {
        void* p = w + off;
        off += (bytes + 255) & ~(size_t)255;
        return p;
    };
    const size_t E1 = (size_t)B * P0 * 16;
    unsigned short* xb  = (unsigned short*)alloc(E1 * 2);        // (P0,B,16)
    unsigned short* t_a = (unsigned short*)alloc(E1 * 2);
    unsigned short* t_b = (unsigned short*)alloc(E1 * 2);
    unsigned short* t_c = (unsigned short*)alloc(E1 * 2);
    unsigned short* h1  = (unsigned short*)alloc((size_t)P1 * B * 64 * 2);
    unsigned short* h2  = (unsigned short*)alloc((size_t)P2 * B * 128 * 2);
    unsigned short* Wt1 = (unsigned short*)alloc(64 * 64 * 2);
    unsigned short* Wt2 = (unsigned short*)alloc(256 * 128 * 2);
    unsigned short* Wt3 = (unsigned short*)alloc(512 * 256 * 2);
    float*          mW1t = (float*)alloc((size_t)512 * 256 * 4);
    float*          mW2t = (float*)alloc((size_t)256 * 512 * 4);
    float*          zblk = (float*)alloc((size_t)NBLK3 * B * 256 * 4);
    float*          zp2  = (float*)alloc((size_t)RSL * B * 256 * 4);
    float*          hh   = (float*)alloc((size_t)B * 512 * 4);

    // ---- precompute: layout transpose + weight prep (power-basis combo) ----
    x2p_kernel<<<(int)(((long)P0 * B * 2 + 255) / 256), 256, 0, stream>>>(x, xb);
    wt_all_kernel<<<(430080 + 255) / 256, 256, 0, stream>>>(
        W1, W2, W3, mW1, mW2, Wt1, Wt2, Wt3, mW1t, mW2t);

    // ---- Stage 1: P0, 16 -> 64, pool 4  (v_k = L^k x) ----
    {
        lmul_v3_kernel<8><<<P0 / 32, 256, 0, stream>>>(xb,  cols1, vals1, t_a);
        lmul_v3_kernel<8><<<P0 / 32, 256, 0, stream>>>(t_a, cols1, vals1, t_b);
        lmul_v3_kernel<8><<<P0 / 32, 256, 0, stream>>>(t_b, cols1, vals1, t_c);
        s1_mm_kernel<<<2048, 256, 0, stream>>>(xb, t_a, t_b, t_c, Wt1, b1, g1, bt1, h1);
    }
    // ---- Stage 2: P1, 64 -> 128, pool 4 ----
    {
        lmul_v3_kernel<32><<<P1 / 8, 256, 0, stream>>>(h1,  cols2, vals2, t_a);
        lmul_v3_kernel<32><<<P1 / 8, 256, 0, stream>>>(t_a, cols2, vals2, t_b);
        lmul_v3_kernel<32><<<P1 / 8, 256, 0, stream>>>(t_b, cols2, vals2, t_c);
        cheb_mm_v5_kernel<64, 128, 4, 2, 4, 6><<<(P1 * B) / 256, 512, 0, stream>>>(
            h1, t_a, t_b, t_c, Wt2, b2, g2, bt2, h2);
    }
    // ---- Stage 3: P2, 128 -> 256, no pool; emits colsum partials ----
    {
        lmul_v3_kernel<64><<<P2 / 4, 256, 0, stream>>>(h2,  cols3, vals3, t_a);
        lmul_v3_kernel<64><<<P2 / 4, 256, 0, stream>>>(t_a, cols3, vals3, t_b);
        lmul_v3_kernel<64><<<P2 / 4, 256, 0, stream>>>(t_b, cols3, vals3, t_c);
        cheb_mm_v5_kernel<128, 256, 2, 4, 1, 7><<<(P2 * B) / 128, 512, 0, stream>>>(
            h2, t_a, t_b, t_c, Wt3, b3, g3, bt3, zblk);
    }
    // ---- z reduce + head ----
    zred_kernel<<<RSL * 4, 256, 0, stream>>>(zblk, zp2);
    headA_kernel<<<16, 256, 0, stream>>>(zp2, mW1t, mb1, hh);
    headB_kernel<<<8, 256, 0, stream>>>(hh, mW2t, mb2, out);

    (void)in_sizes; (void)n_in; (void)out_size; (void)ws_size;
}

// Round 10
// 379.170 us; speedup vs baseline: 1.1881x; 1.0119x over previous
//
#include <hip/hip_runtime.h>
#include <hip/hip_bf16.h>

namespace {

constexpr int B  = 4;
constexpr int P0 = 196608, P1 = 49152, P2 = 12288;
constexpr int DEG = 8;
constexpr float EPS = 1e-5f;
constexpr int NBLK3 = (P2 * B) / 64;   // 768 zblk partial rows
constexpr int RSL = 16;                // zred slices
constexpr int RPB = NBLK3 / RSL;       // 48 zblk rows per slice

typedef __attribute__((ext_vector_type(4))) float f32x4;
typedef __attribute__((ext_vector_type(8))) short s16x8;

__device__ __forceinline__ float b2f(unsigned short u) {
    union { unsigned int i; float f; } c; c.i = (unsigned int)u << 16; return c.f;
}
__device__ __forceinline__ unsigned short f2b(float f) {
    __hip_bfloat16 h = __float2bfloat16(f);   // RNE
    return *reinterpret_cast<unsigned short*>(&h);
}

// async global->LDS: 16B per lane, LDS dest = uniform base + lane*16
__device__ __forceinline__ void gload_lds16(const void* gsrc, void* ldst) {
    __builtin_amdgcn_global_load_lds(
        (const __attribute__((address_space(1))) void*)gsrc,
        (__attribute__((address_space(3))) void*)ldst, 16, 0, 0);
}

// Chebyshev->power-basis weight combo:
//   xk@W = v0@(W0-W2) + v1@(W1-3W3) + v2@(2W2) + v3@(4W3),  v_k = L^k x.
__device__ __forceinline__ float chebw(const float* __restrict__ W,
                                       int k, int n, int N, int Cin) {
    int t = k / Cin, c = k - t * Cin;
    float v = W[(size_t)k * N + n];
    if (t == 0)      v = v - W[(size_t)(2 * Cin + c) * N + n];
    else if (t == 1) v = v - 3.f * W[(size_t)(3 * Cin + c) * N + n];
    else if (t == 2) v = 2.f * v;
    else             v = 4.f * v;
    return v;
}

// ---------------------------------------------------------------------------
// x: (B,P0,16) fp32  ->  xb: (P0,B,16) bf16
// ---------------------------------------------------------------------------
__global__ __launch_bounds__(256)
void x2p_kernel(const float* __restrict__ in, unsigned short* __restrict__ out)
{
    long idx = (long)blockIdx.x * blockDim.x + threadIdx.x;   // P0*B*2 total
    if (idx >= (long)P0 * B * 2) return;
    int  h = (int)(idx & 1);
    int  b = (int)((idx >> 1) & 3);
    long p = idx >> 3;
    const float* src = in + ((size_t)b * P0 + p) * 16 + h * 8;
    float4 v0 = *(const float4*)src;
    float4 v1 = *(const float4*)(src + 4);
    union { uint4 u; unsigned short s[8]; } o;
    o.s[0] = f2b(v0.x); o.s[1] = f2b(v0.y); o.s[2] = f2b(v0.z); o.s[3] = f2b(v0.w);
    o.s[4] = f2b(v1.x); o.s[5] = f2b(v1.y); o.s[6] = f2b(v1.z); o.s[7] = f2b(v1.w);
    *(uint4*)&out[((size_t)p * B + b) * 16 + h * 8] = o.u;
}

// ---------------------------------------------------------------------------
// Weight prep, one launch: W1/W2/W3 -> power-basis-combined, transposed bf16;
// mW1/mW2 -> fp32 transposed (contiguous head dot-products).
// ---------------------------------------------------------------------------
__global__ __launch_bounds__(256)
void wt_all_kernel(const float* __restrict__ W1, const float* __restrict__ W2,
                   const float* __restrict__ W3,
                   const float* __restrict__ mW1, const float* __restrict__ mW2,
                   unsigned short* __restrict__ Wt1, unsigned short* __restrict__ Wt2,
                   unsigned short* __restrict__ Wt3,
                   float* __restrict__ mW1t, float* __restrict__ mW2t)
{
    int i = blockIdx.x * 256 + threadIdx.x;
    if (i < 4096) {                       // W1: K=64 (Cin=16), N=64
        int n = i % 64, k = i / 64;
        Wt1[n * 64 + k] = f2b(chebw(W1, k, n, 64, 16));
    } else if (i < 36864) {               // W2: K=256 (Cin=64), N=128
        int j = i - 4096;
        int n = j % 128, k = j / 128;
        Wt2[n * 256 + k] = f2b(chebw(W2, k, n, 128, 64));
    } else if (i < 167936) {              // W3: K=512 (Cin=128), N=256
        int j = i - 36864;
        int n = j % 256, k = j / 256;
        Wt3[n * 512 + k] = f2b(chebw(W3, k, n, 256, 128));
    } else if (i < 299008) {              // mW1: (256,512) -> (512,256) fp32
        int j = i - 167936;
        int n = j % 512, k = j / 512;
        mW1t[(size_t)n * 256 + k] = mW1[j];
    } else if (i < 430080) {              // mW2: (512,256) -> (256,512) fp32
        int j = i - 299008;
        int n = j % 256, k = j / 256;
        mW2t[(size_t)n * 512 + k] = mW2[j];
    }
}

// ---------------------------------------------------------------------------
// Pure sparse gather step on (P, B*C) bf16 rows, fp32 accum (power basis).
// ---------------------------------------------------------------------------
template <int CV8>
__global__ __launch_bounds__(256)
void lmul_v3_kernel(const unsigned short* __restrict__ in,
                    const int* __restrict__ cols, const float* __restrict__ vals,
                    unsigned short* __restrict__ out)
{
    constexpr int ROWS = 256 / CV8;
    __shared__ int   cs[ROWS * DEG];
    __shared__ float vs[ROWS * DEG];
    const int tid = threadIdx.x;
    const long r0 = (long)blockIdx.x * ROWS;
    if (tid < ROWS * DEG) {
        cs[tid] = cols[r0 * DEG + tid];
        vs[tid] = vals[r0 * DEG + tid];
    }
    __syncthreads();

    const int v  = tid & (CV8 - 1);
    const int lr = tid / CV8;
    const uint4* in16 = (const uint4*)in;

    float acc[8] = {0.f,0.f,0.f,0.f,0.f,0.f,0.f,0.f};
#pragma unroll
    for (int d = 0; d < DEG; ++d) {
        int   col = cs[lr * DEG + d];
        float w   = vs[lr * DEG + d];
        union { uint4 u; unsigned short s[8]; } x;
        x.u = in16[(size_t)col * CV8 + v];
#pragma unroll
        for (int j = 0; j < 8; ++j) acc[j] = fmaf(w, b2f(x.s[j]), acc[j]);
    }
    union { uint4 u; unsigned short s[8]; } ou;
#pragma unroll
    for (int j = 0; j < 8; ++j) ou.s[j] = f2b(acc[j]);
    ((uint4*)out)[(size_t)(r0 + lr) * CV8 + v] = ou.u;
}

// ---------------------------------------------------------------------------
// Stage-1 fused MM: KC=64, COUT=64, pool 4. W resident in registers,
// A-fragments read directly from global; grid-stride over 16-row wave-tiles.
// ---------------------------------------------------------------------------
__global__ __launch_bounds__(256)
void s1_mm_kernel(const unsigned short* __restrict__ t0,
                  const unsigned short* __restrict__ t1,
                  const unsigned short* __restrict__ t2,
                  const unsigned short* __restrict__ t3,
                  const unsigned short* __restrict__ Wt,
                  const float* __restrict__ bias,
                  const float* __restrict__ gam,
                  const float* __restrict__ bet,
                  unsigned short* __restrict__ out)
{
    const int wave = threadIdx.x >> 6;
    const int lane = threadIdx.x & 63;
    const int g    = lane >> 4;
    const int c16  = lane & 15;

    s16x8 wf[2][4];
#pragma unroll
    for (int ks = 0; ks < 2; ++ks)
#pragma unroll
        for (int n = 0; n < 4; ++n)
            wf[ks][n] = *(const s16x8*)&Wt[(size_t)(n * 16 + c16) * 64 + ks * 32 + g * 8];

    float bz[4], gz[4], tz[4];
#pragma unroll
    for (int n = 0; n < 4; ++n) {
        bz[n] = bias[n * 16 + c16];
        gz[n] = gam [n * 16 + c16];
        tz[n] = bet [n * 16 + c16];
    }

    const unsigned short* tb[4] = { t0, t1, t2, t3 };
    const int term0  = g >> 1;
    const int coloff = (g & 1) * 8;
    const int bb     = c16 >> 2;
    const int px     = c16 & 3;

    constexpr int NT = P0 / 4;
    const int wg     = blockIdx.x * 4 + wave;
    const int wstep  = gridDim.x * 4;

    for (int t = wg; t < NT; t += wstep) {
        size_t rowbase = ((size_t)(t * 4 + px) * 4 + bb) * 16 + coloff;
        s16x8 a0 = *(const s16x8*)&tb[term0    ][rowbase];
        s16x8 a1 = *(const s16x8*)&tb[term0 + 2][rowbase];

        f32x4 acc[4];
#pragma unroll
        for (int n = 0; n < 4; ++n) acc[n] = (f32x4){bz[n], bz[n], bz[n], bz[n]};
#pragma unroll
        for (int n = 0; n < 4; ++n)
            acc[n] = __builtin_amdgcn_mfma_f32_16x16x32_bf16(a0, wf[0][n], acc[n], 0, 0, 0);
#pragma unroll
        for (int n = 0; n < 4; ++n)
            acc[n] = __builtin_amdgcn_mfma_f32_16x16x32_bf16(a1, wf[1][n], acc[n], 0, 0, 0);

        float s[4] = {0,0,0,0}, q[4] = {0,0,0,0};
#pragma unroll
        for (int n = 0; n < 4; ++n)
#pragma unroll
            for (int r = 0; r < 4; ++r) {
                float v = acc[n][r];
                s[r] += v; q[r] += v * v;
            }
#pragma unroll
        for (int msk = 1; msk < 16; msk <<= 1)
#pragma unroll
            for (int r = 0; r < 4; ++r) {
                s[r] += __shfl_xor(s[r], msk, 64);
                q[r] += __shfl_xor(q[r], msk, 64);
            }
        float mu[4], rs[4];
#pragma unroll
        for (int r = 0; r < 4; ++r) {
            mu[r] = s[r] * (1.f / 64.f);
            float var = q[r] * (1.f / 64.f) - mu[r] * mu[r];
            rs[r] = rsqrtf(var + EPS);
        }
        size_t ro = ((size_t)t * 4 + g) * 64;
#pragma unroll
        for (int n = 0; n < 4; ++n) {
            float pv = 0.f;
#pragma unroll
            for (int r = 0; r < 4; ++r) {
                float h = fmaf(gz[n] * rs[r], acc[n][r] - mu[r], tz[n]);
                pv += fmaxf(h, 0.f);
            }
            out[ro + n * 16 + c16] = f2b(pv * 0.25f);
        }
    }
}

// ---------------------------------------------------------------------------
// Stages 2/3 fused MM v6: async global_load_lds + TRIPLE-buffered LDS +
// counted s_waitcnt vmcnt(6) / raw s_barrier (T4): 2 chunks (12 loads/wave)
// stay in flight continuously; no full drain in the main loop.
// Per chunk each wave issues exactly ACALLS+WCALLS = 6 gload_lds16.
// Swizzle via inverse-swizzled per-lane global source + linear LDS dest.
// ---------------------------------------------------------------------------
template <int CIN, int COUT, int GM, int GN, int POOL, int LOG2CIN>
__global__ __launch_bounds__(512)
void cheb_mm_v6_kernel(const unsigned short* __restrict__ t0,
                       const unsigned short* __restrict__ t1,
                       const unsigned short* __restrict__ t2,
                       const unsigned short* __restrict__ t3,
                       const unsigned short* __restrict__ Wt,
                       const float* __restrict__ bias,
                       const float* __restrict__ gam,
                       const float* __restrict__ bet,
                       void* __restrict__ outv)
{
    constexpr int KC     = 4 * CIN;
    constexpr int BM     = GM * 64;
    constexpr int NKCH   = KC / 64;
    constexpr int ACALLS = BM / 64;     // gload_lds calls per wave (A)
    constexpr int WCALLS = COUT / 64;   // ACALLS+WCALLS == 6 for both stages

    __shared__ unsigned short As[3][BM * 64];     // 128B/row, triple-buffered
    __shared__ unsigned short Ws[3][COUT * 64];
    __shared__ float sq[BM][GN][2];

    const int tid  = threadIdx.x;
    const int wv   = tid >> 6;
    const int gm   = wv / GN;
    const int gn   = wv % GN;
    const int lane = tid & 63;
    const int g    = lane >> 4;
    const int c16  = lane & 15;

    const unsigned short* tb[4] = { t0, t1, t2, t3 };

    float bz[4], gz[4], tz[4];
#pragma unroll
    for (int n = 0; n < 4; ++n) {
        int col = gn * 64 + n * 16 + c16;
        bz[n] = bias[col]; gz[n] = gam[col]; tz[n] = bet[col];
    }

    // consume bias BEFORE staging so compiler's bias-wait precedes prefetches
    f32x4 acc[4][4];
#pragma unroll
    for (int m = 0; m < 4; ++m)
#pragma unroll
        for (int n = 0; n < 4; ++n)
            acc[m][n] = (f32x4){bz[n], bz[n], bz[n], bz[n]};

    // ---- async stage of chunk kc into buffer bb (fire-and-forget) ----
    auto stage = [&](int kc, int bb) {
        int term, cbase;
        if constexpr (LOG2CIN == 6) { term = kc;      cbase = 0; }
        else                        { term = kc >> 1; cbase = (kc & 1) * 64; }
        const unsigned short* tp = tb[term];
#pragma unroll
        for (int a = 0; a < ACALLS; ++a) {
            int ci   = wv * ACALLS + a;
            int row  = ci * 8 + (lane >> 3);
            int srcb = ((lane & 7) * 16) ^ ((row & 7) << 4);   // inverse swizzle
            size_t rowbase;
            if constexpr (POOL == 4) {
                int pix = blockIdx.x * (BM / 4) + ((row >> 4) << 2) + (row & 3);
                int rb  = (row >> 2) & 3;
                rowbase = ((size_t)pix * B + rb) * CIN + cbase;
            } else {
                rowbase = ((size_t)(blockIdx.x * BM + row)) * CIN + cbase;
            }
            gload_lds16((const char*)(tp + rowbase) + srcb, &As[bb][ci * 512]);
        }
#pragma unroll
        for (int a = 0; a < WCALLS; ++a) {
            int ci   = wv * WCALLS + a;
            int co   = ci * 8 + (lane >> 3);
            int srcb = ((lane & 7) * 16) ^ ((co & 7) << 4);
            gload_lds16((const char*)(Wt + (size_t)co * KC + kc * 64) + srcb,
                        &Ws[bb][ci * 512]);
        }
    };

    stage(0, 0);
    stage(1, 1);
    for (int kc = 0; kc < NKCH; ++kc) {
        // wait chunk kc's 6 loads (per wave); keep kc+1's 6 in flight
        if (kc + 1 < NKCH) asm volatile("s_waitcnt vmcnt(6)" ::: "memory");
        else               asm volatile("s_waitcnt vmcnt(0)" ::: "memory");
        __builtin_amdgcn_s_barrier();      // all waves' chunk-kc loads landed
        if (kc + 2 < NKCH) stage(kc + 2, (kc + 2) % 3);   // overlaps MFMA below
        const char* Ab = (const char*)As[kc % 3];
        const char* Wb = (const char*)Ws[kc % 3];
#pragma unroll
        for (int ks = 0; ks < 2; ++ks) {
            const int swz = (ks * 64 + g * 16) ^ ((c16 & 7) << 4);
            s16x8 a[4], bw[4];
#pragma unroll
            for (int m = 0; m < 4; ++m)
                a[m] = *(const s16x8*)(Ab + (gm * 64 + m * 16 + c16) * 128 + swz);
#pragma unroll
            for (int n = 0; n < 4; ++n)
                bw[n] = *(const s16x8*)(Wb + (gn * 64 + n * 16 + c16) * 128 + swz);
#pragma unroll
            for (int n = 0; n < 4; ++n)
#pragma unroll
                for (int m = 0; m < 4; ++m)
                    acc[m][n] = __builtin_amdgcn_mfma_f32_16x16x32_bf16(a[m], bw[n], acc[m][n], 0, 0, 0);
        }
    }

    // ---- LN stats: per-wave column-slice partials, cross-wave via sq ----
    float sm[4][4], qm[4][4];
#pragma unroll
    for (int m = 0; m < 4; ++m)
#pragma unroll
        for (int r = 0; r < 4; ++r) { sm[m][r] = 0.f; qm[m][r] = 0.f; }
#pragma unroll
    for (int m = 0; m < 4; ++m)
#pragma unroll
        for (int n = 0; n < 4; ++n)
#pragma unroll
            for (int r = 0; r < 4; ++r) {
                float v = acc[m][n][r];
                sm[m][r] += v; qm[m][r] += v * v;
            }
#pragma unroll
    for (int msk = 1; msk < 16; msk <<= 1)
#pragma unroll
        for (int m = 0; m < 4; ++m)
#pragma unroll
            for (int r = 0; r < 4; ++r) {
                sm[m][r] += __shfl_xor(sm[m][r], msk, 64);
                qm[m][r] += __shfl_xor(qm[m][r], msk, 64);
            }
    __syncthreads();
    if (c16 == 0) {
#pragma unroll
        for (int m = 0; m < 4; ++m)
#pragma unroll
            for (int r = 0; r < 4; ++r) {
                sq[gm * 64 + m * 16 + g * 4 + r][gn][0] = sm[m][r];
                sq[gm * 64 + m * 16 + g * 4 + r][gn][1] = qm[m][r];
            }
    }
    __syncthreads();
    float mu[4][4], rs[4][4];
#pragma unroll
    for (int m = 0; m < 4; ++m)
#pragma unroll
        for (int r = 0; r < 4; ++r) {
            int row = gm * 64 + m * 16 + g * 4 + r;
            float ss = 0.f, qq = 0.f;
#pragma unroll
            for (int j = 0; j < GN; ++j) { ss += sq[row][j][0]; qq += sq[row][j][1]; }
            mu[m][r] = ss * (1.f / COUT);
            float var = qq * (1.f / COUT) - mu[m][r] * mu[m][r];
            rs[m][r] = rsqrtf(var + EPS);
        }

    if constexpr (POOL == 4) {
        unsigned short* outp = (unsigned short*)outv;
#pragma unroll
        for (int m = 0; m < 4; ++m) {
            size_t ro = ((size_t)(blockIdx.x * (BM / 16) + gm * 4 + m) * B + g) * COUT + gn * 64;
#pragma unroll
            for (int n = 0; n < 4; ++n) {
                float pv = 0.f;
#pragma unroll
                for (int r = 0; r < 4; ++r) {
                    float h = fmaf(gz[n] * rs[m][r], acc[m][n][r] - mu[m][r], tz[n]);
                    pv += fmaxf(h, 0.f);
                }
                outp[ro + n * 16 + c16] = f2b(pv * 0.25f);
            }
        }
    } else {
        float part[4][4];   // [n][r]; flat-row batch = reg index r
#pragma unroll
        for (int n = 0; n < 4; ++n)
#pragma unroll
            for (int r = 0; r < 4; ++r) part[n][r] = 0.f;
#pragma unroll
        for (int m = 0; m < 4; ++m)
#pragma unroll
            for (int n = 0; n < 4; ++n)
#pragma unroll
                for (int r = 0; r < 4; ++r) {
                    float h = fmaf(gz[n] * rs[m][r], acc[m][n][r] - mu[m][r], tz[n]);
                    part[n][r] += fmaxf(h, 0.f);
                }
#pragma unroll
        for (int n = 0; n < 4; ++n)
#pragma unroll
            for (int r = 0; r < 4; ++r) {
                part[n][r] += __shfl_xor(part[n][r], 16, 64);
                part[n][r] += __shfl_xor(part[n][r], 32, 64);
            }
        if (g == 0) {
            float* zb = (float*)outv + ((size_t)(blockIdx.x * GM + gm)) * (B * COUT);
#pragma unroll
            for (int n = 0; n < 4; ++n)
#pragma unroll
                for (int r = 0; r < 4; ++r)
                    zb[(size_t)r * COUT + gn * 64 + n * 16 + c16] = part[n][r];
        }
    }
}

// ---------------------------------------------------------------------------
// zblk (768, B*256) -> zp2 (RSL, B*256): coalesced parallel column reduce.
// ---------------------------------------------------------------------------
__global__ __launch_bounds__(256)
void zred_kernel(const float* __restrict__ zblk, float* __restrict__ zp2)
{
    int s   = blockIdx.x >> 2;
    int col = (blockIdx.x & 3) * 256 + threadIdx.x;
    float acc = 0.f;
#pragma unroll 8
    for (int r = 0; r < RPB; ++r)
        acc += zblk[(size_t)(s * RPB + r) * (B * 256) + col];
    zp2[(size_t)s * (B * 256) + col] = acc;
}

// ---------------------------------------------------------------------------
// Head stage A: z = (reduce zp2)/P2; hh[b][j] = relu(z[b]·mW1t[j] + mb1[j]).
// ---------------------------------------------------------------------------
__global__ __launch_bounds__(256)
void headA_kernel(const float* __restrict__ zp2, const float* __restrict__ mW1t,
                  const float* __restrict__ mb1, float* __restrict__ hh)
{
    __shared__ float zs[B * 256];
    __shared__ float ph[256];
    const int tid = threadIdx.x;
    for (int idx = tid; idx < B * 256; idx += 256) {
        float s = 0.f;
#pragma unroll
        for (int sl = 0; sl < RSL; ++sl) s += zp2[(size_t)sl * (B * 256) + idx];
        zs[idx] = s * (1.f / P2);
    }
    __syncthreads();
    const int jl = tid & 31, b = (tid >> 5) & 3, ig = tid >> 7;
    const int j  = blockIdx.x * 32 + jl;
    const float4* wrow = (const float4*)&mW1t[(size_t)j * 256 + ig * 128];
    const float*  zb   = &zs[b * 256 + ig * 128];
    float acc = 0.f;
#pragma unroll
    for (int i4 = 0; i4 < 32; ++i4) {
        float4 wv = wrow[i4];
        acc += zb[i4*4]*wv.x + zb[i4*4+1]*wv.y + zb[i4*4+2]*wv.z + zb[i4*4+3]*wv.w;
    }
    ph[tid] = acc;
    __syncthreads();
    if (tid < 128) {
        float a = ph[tid] + ph[tid + 128] + mb1[j];
        hh[b * 512 + j] = fmaxf(a, 0.f);
    }
}

// ---------------------------------------------------------------------------
// Head stage B: out[b][c] = hh[b]·mW2t[c] + mb2[c].
// ---------------------------------------------------------------------------
__global__ __launch_bounds__(256)
void headB_kernel(const float* __restrict__ hh, const float* __restrict__ mW2t,
                  const float* __restrict__ mb2, float* __restrict__ out)
{
    __shared__ float hs[B * 512];
    __shared__ float ph[256];
    const int tid = threadIdx.x;
    for (int idx = tid; idx < B * 512; idx += 256) hs[idx] = hh[idx];
    __syncthreads();
    const int cl = tid & 31, b = (tid >> 5) & 3, ig = tid >> 7;
    const int c  = blockIdx.x * 32 + cl;
    const float4* wrow = (const float4*)&mW2t[(size_t)c * 512 + ig * 256];
    const float*  hb   = &hs[b * 512 + ig * 256];
    float acc = 0.f;
#pragma unroll
    for (int j4 = 0; j4 < 64; ++j4) {
        float4 wv = wrow[j4];
        acc += hb[j4*4]*wv.x + hb[j4*4+1]*wv.y + hb[j4*4+2]*wv.z + hb[j4*4+3]*wv.w;
    }
    ph[tid] = acc;
    __syncthreads();
    if (tid < 128)
        out[b * 256 + c] = ph[tid] + ph[tid + 128] + mb2[c];
}

} // anonymous namespace

extern "C" void kernel_launch(void* const* d_in, const int* in_sizes, int n_in,
                              void* d_out, int out_size, void* d_ws, size_t ws_size,
                              hipStream_t stream)
{
    const float* x     = (const float*)d_in[0];
    const int*   cols1 = (const int*)  d_in[1];
    const float* vals1 = (const float*)d_in[2];
    const int*   cols2 = (const int*)  d_in[3];
    const float* vals2 = (const float*)d_in[4];
    const int*   cols3 = (const int*)  d_in[5];
    const float* vals3 = (const float*)d_in[6];
    const float* W1  = (const float*)d_in[7];
    const float* b1  = (const float*)d_in[8];
    const float* g1  = (const float*)d_in[9];
    const float* bt1 = (const float*)d_in[10];
    const float* W2  = (const float*)d_in[11];
    const float* b2  = (const float*)d_in[12];
    const float* g2  = (const float*)d_in[13];
    const float* bt2 = (const float*)d_in[14];
    const float* W3  = (const float*)d_in[15];
    const float* b3  = (const float*)d_in[16];
    const float* g3  = (const float*)d_in[17];
    const float* bt3 = (const float*)d_in[18];
    const float* mW1 = (const float*)d_in[19];
    const float* mb1 = (const float*)d_in[20];
    const float* mW2 = (const float*)d_in[21];
    const float* mb2 = (const float*)d_in[22];
    float* out = (float*)d_out;

    // ---- workspace layout (256B-aligned slots) ----
    char* w = (char*)d_ws;
    size_t off = 0;
    auto alloc = [&](size_t bytes) -> void* {
        void* p = w + off;
        off += (bytes + 255) & ~(size_t)255;
        return p;
    };
    const size_t E1 = (size_t)B * P0 * 16;
    unsigned short* xb  = (unsigned short*)alloc(E1 * 2);        // (P0,B,16)
    unsigned short* t_a = (unsigned short*)alloc(E1 * 2);
    unsigned short* t_b = (unsigned short*)alloc(E1 * 2);
    unsigned short* t_c = (unsigned short*)alloc(E1 * 2);
    unsigned short* h1  = (unsigned short*)alloc((size_t)P1 * B * 64 * 2);
    unsigned short* h2  = (unsigned short*)alloc((size_t)P2 * B * 128 * 2);
    unsigned short* Wt1 = (unsigned short*)alloc(64 * 64 * 2);
    unsigned short* Wt2 = (unsigned short*)alloc(256 * 128 * 2);
    unsigned short* Wt3 = (unsigned short*)alloc(512 * 256 * 2);
    float*          mW1t = (float*)alloc((size_t)512 * 256 * 4);
    float*          mW2t = (float*)alloc((size_t)256 * 512 * 4);
    float*          zblk = (float*)alloc((size_t)NBLK3 * B * 256 * 4);
    float*          zp2  = (float*)alloc((size_t)RSL * B * 256 * 4);
    float*          hh   = (float*)alloc((size_t)B * 512 * 4);

    // ---- precompute: layout transpose + weight prep (power-basis combo) ----
    x2p_kernel<<<(int)(((long)P0 * B * 2 + 255) / 256), 256, 0, stream>>>(x, xb);
    wt_all_kernel<<<(430080 + 255) / 256, 256, 0, stream>>>(
        W1, W2, W3, mW1, mW2, Wt1, Wt2, Wt3, mW1t, mW2t);

    // ---- Stage 1: P0, 16 -> 64, pool 4  (v_k = L^k x) ----
    {
        lmul_v3_kernel<8><<<P0 / 32, 256, 0, stream>>>(xb,  cols1, vals1, t_a);
        lmul_v3_kernel<8><<<P0 / 32, 256, 0, stream>>>(t_a, cols1, vals1, t_b);
        lmul_v3_kernel<8><<<P0 / 32, 256, 0, stream>>>(t_b, cols1, vals1, t_c);
        s1_mm_kernel<<<2048, 256, 0, stream>>>(xb, t_a, t_b, t_c, Wt1, b1, g1, bt1, h1);
    }
    // ---- Stage 2: P1, 64 -> 128, pool 4 ----
    {
        lmul_v3_kernel<32><<<P1 / 8, 256, 0, stream>>>(h1,  cols2, vals2, t_a);
        lmul_v3_kernel<32><<<P1 / 8, 256, 0, stream>>>(t_a, cols2, vals2, t_b);
        lmul_v3_kernel<32><<<P1 / 8, 256, 0, stream>>>(t_b, cols2, vals2, t_c);
        cheb_mm_v6_kernel<64, 128, 4, 2, 4, 6><<<(P1 * B) / 256, 512, 0, stream>>>(
            h1, t_a, t_b, t_c, Wt2, b2, g2, bt2, h2);
    }
    // ---- Stage 3: P2, 128 -> 256, no pool; emits colsum partials ----
    {
        lmul_v3_kernel<64><<<P2 / 4, 256, 0, stream>>>(h2,  cols3, vals3, t_a);
        lmul_v3_kernel<64><<<P2 / 4, 256, 0, stream>>>(t_a, cols3, vals3, t_b);
        lmul_v3_kernel<64><<<P2 / 4, 256, 0, stream>>>(t_b, cols3, vals3, t_c);
        cheb_mm_v6_kernel<128, 256, 2, 4, 1, 7><<<(P2 * B) / 128, 512, 0, stream>>>(
            h2, t_a, t_b, t_c, Wt3, b3, g3, bt3, zblk);
    }
    // ---- z reduce + head ----
    zred_kernel<<<RSL * 4, 256, 0, stream>>>(zblk, zp2);
    headA_kernel<<<16, 256, 0, stream>>>(zp2, mW1t, mb1, hh);
    headB_kernel<<<8, 256, 0, stream>>>(hh, mW2t, mb2, out);

    (void)in_sizes; (void)n_in; (void)out_size; (void)ws_size;
}